// Round 5
// baseline (1776.553 us; speedup 1.0000x reference)
//
#include <hip/hip_runtime.h>
#include <hip/hip_bf16.h>
#include <math.h>

#define N 320
#define NN (N * N)          // 102400
#define SST 324             // LDS fp32 row stride for S scratch

typedef float f32x16 __attribute__((ext_vector_type(16)));
typedef short s16x8  __attribute__((ext_vector_type(8)));

#define MFMA32(a, b, c) __builtin_amdgcn_mfma_f32_32x32x16_bf16((a), (b), (c), 0, 0, 0)

union U4V { uint4 q; s16x8 v; };
union UAV { unsigned u[4]; s16x8 v; };

// truncation split via v_perm_b32: x = hi + lo, both bf16 (combined rel err ~2^-16)
__device__ inline void split2p(float x0, float x1, unsigned& hi, unsigned& lo) {
    unsigned u0 = __float_as_uint(x0), u1 = __float_as_uint(x1);
    hi = __builtin_amdgcn_perm(u1, u0, 0x07060302u);
    float d0 = x0 - __uint_as_float(u0 & 0xFFFF0000u);
    float d1 = x1 - __uint_as_float(u1 & 0xFFFF0000u);
    lo = __builtin_amdgcn_perm(__float_as_uint(d1), __float_as_uint(d0), 0x07060302u);
}

// ================= merged prep kernel =================
// blocks 0..99   : zero wbuf (100*256 float4 = 102400 floats)
// block  100     : colsum[e] = sum_t s[t][e]
// blocks 101..150: pack s^T -> A-frags (4 frag-blocks per block)
// blocks 151..200: pack W^T -> B-frags
__global__ __launch_bounds__(256) void prep_kernel(
    const float* __restrict__ s, const float* __restrict__ W,
    float* __restrict__ wbuf, float* __restrict__ colsum,
    uint4* __restrict__ spH, uint4* __restrict__ spL,
    uint4* __restrict__ wpH, uint4* __restrict__ wpL)
{
    const int blk = blockIdx.x;
    const int tid = threadIdx.x;

    if (blk < 100) {
        ((float4*)wbuf)[blk * 256 + tid] = make_float4(0.f, 0.f, 0.f, 0.f);
        return;
    }
    if (blk == 100) {
        for (int e = tid; e < N; e += 256) {
            float a0 = 0.f, a1 = 0.f, a2 = 0.f, a3 = 0.f;
            for (int t = 0; t < N; t += 4) {
                a0 += s[(size_t)(t + 0) * N + e];
                a1 += s[(size_t)(t + 1) * N + e];
                a2 += s[(size_t)(t + 2) * N + e];
                a3 += s[(size_t)(t + 3) * N + e];
            }
            colsum[e] = (a0 + a1) + (a2 + a3);
        }
        return;
    }
    if (blk <= 150) {
        int fb = (blk - 101) * 4 + (tid >> 6);   // frag-block 0..199 = et*20+ts
        int l = tid & 63;
        int et = fb / 20, ts = fb % 20;
        int e = et * 32 + (l & 31);
        int t0 = ts * 16 + (l >> 5) * 8;
        unsigned hi[4], lo[4];
#pragma unroll
        for (int d = 0; d < 4; ++d)
            split2p(s[(size_t)(t0 + 2 * d) * N + e], s[(size_t)(t0 + 2 * d + 1) * N + e],
                    hi[d], lo[d]);
        spH[fb * 64 + l] = make_uint4(hi[0], hi[1], hi[2], hi[3]);
        spL[fb * 64 + l] = make_uint4(lo[0], lo[1], lo[2], lo[3]);
        return;
    }
    {
        int fb = (blk - 151) * 4 + (tid >> 6);   // frag-block 0..199 = jt*20+ks
        int l = tid & 63;
        int jt = fb / 20, ks = fb % 20;
        int j = jt * 32 + (l & 31);
        int k0 = ks * 16 + (l >> 5) * 8;
        const float* wr = W + (size_t)j * N + k0;
        unsigned hi[4], lo[4];
#pragma unroll
        for (int d = 0; d < 4; ++d) split2p(wr[2 * d], wr[2 * d + 1], hi[d], lo[d]);
        wpH[fb * 64 + l] = make_uint4(hi[0], hi[1], hi[2], hi[3]);
        wpL[fb * 64 + l] = make_uint4(lo[0], lo[1], lo[2], lo[3]);
    }
}

// ================= fused MFMA kernel: per (e-slab 32, i) =================
// 1-D grid (3200), XCD swizzle: all 10 e-slabs of one i on one XCD (L2 reuse of F_i).
__global__ __launch_bounds__(640, 5) void fused_kernel(
    const float* __restrict__ fut,
    const uint4* __restrict__ spH, const uint4* __restrict__ spL,
    const uint4* __restrict__ wpH, const uint4* __restrict__ wpL,
    const float* __restrict__ bvec, const float* __restrict__ colsum,
    float* __restrict__ w)
{
    const int bid = blockIdx.x;
    const int i   = (bid / 80) * 8 + (bid & 7);
    const int et  = (bid >> 3) % 10;
    const int tid = threadIdx.x;
    const int wid = tid >> 6;         // wave 0..9 = 32-wide column tile
    const int lane = tid & 63;
    const int l31 = lane & 31;
    const int hf  = lane >> 5;

    // G in LDS: frag-linear, XOR-swizzled 16B chunks (R4-verified: 0 conflicts).
    __shared__ union {
        unsigned short G[2][40 * 32 * 8];   // [hi/lo] 20KB each
        float S[32 * SST];                  // softmax scratch
    } sm;
    __shared__ float csh[32];
    __shared__ float Mfin[32];
    __shared__ float Ifin[32];

    if (tid < 32) csh[tid] = colsum[et * 32 + tid];

    // ---------------- phase A: G = s^T @ F_i ----------------
    f32x16 accA, accB;
#pragma unroll
    for (int r = 0; r < 16; ++r) { accA[r] = 0.f; accB[r] = 0.f; }

    const float* fbase = fut + (size_t)i * NN + (size_t)(hf * 8) * N + wid * 32 + l31;
    const uint4* aH = spH + (size_t)(et * 20) * 64 + lane;
    const uint4* aL = spL + (size_t)(et * 20) * 64 + lane;

    float fbuf[2][8];
    uint4 ahb[2], alb[2];
    {
        const float* fp = fbase;
#pragma unroll
        for (int j = 0; j < 8; ++j) fbuf[0][j] = fp[(size_t)j * N];
        ahb[0] = aH[0]; alb[0] = aL[0];
    }
#pragma unroll 2
    for (int ts = 0; ts < 20; ++ts) {
        const int cur = ts & 1, nxt = cur ^ 1;
        if (ts < 19) {
            const float* fp = fbase + (size_t)((ts + 1) * 16) * N;
#pragma unroll
            for (int j = 0; j < 8; ++j) fbuf[nxt][j] = fp[(size_t)j * N];
            ahb[nxt] = aH[(ts + 1) * 64];
            alb[nxt] = aL[(ts + 1) * 64];
        }
        UAV bh, bl;
#pragma unroll
        for (int d = 0; d < 4; ++d)
            split2p(fbuf[cur][2 * d], fbuf[cur][2 * d + 1], bh.u[d], bl.u[d]);
        U4V ah; ah.q = ahb[cur];
        U4V al; al.q = alb[cur];
        accA = MFMA32(ah.v, bh.v, accA);
        accB = MFMA32(al.v, bh.v, accB);
        accB = MFMA32(ah.v, bl.v, accB);
    }

    // G -> LDS bf16 hi/lo in frag-linear swizzled layout
    {
        const int c  = wid * 4 + (l31 >> 3);
        const int jj = l31 & 7;
        const int sw = c & 7;
        unsigned short* GH = sm.G[0];
        unsigned short* GL = sm.G[1];
#pragma unroll
        for (int r = 0; r < 16; ++r) {
            int e = (r & 3) + ((r >> 2) << 3) + (hf << 2);
            float x = accA[r] + accB[r];
            unsigned u = __float_as_uint(x);
            float d = x - __uint_as_float(u & 0xFFFF0000u);
            int off = (c * 32 + (e ^ sw)) * 8 + jj;
            GH[off] = (unsigned short)(u >> 16);
            GL[off] = (unsigned short)(__float_as_uint(d) >> 16);
        }
    }
    __syncthreads();   // B1: G + csh visible

    // ---------------- phase B: S = G @ W^T (+ bias) ----------------
    f32x16 acc2A, acc2B;
#pragma unroll
    for (int r = 0; r < 16; ++r) { acc2A[r] = 0.f; acc2B[r] = 0.f; }

    const uint4* bH = wpH + (size_t)(wid * 20) * 64 + lane;
    const uint4* bL = wpL + (size_t)(wid * 20) * 64 + lane;
    const unsigned short* GH = sm.G[0];
    const unsigned short* GL = sm.G[1];

    uint4 whb[2], wlb[2];
    s16x8 gahb[2], galb[2];
    {
        whb[0] = bH[0]; wlb[0] = bL[0];
        int c0 = hf;
        int aoff = (c0 * 32 + (l31 ^ (c0 & 7))) * 8;
        gahb[0] = *(const s16x8*)&GH[aoff];
        galb[0] = *(const s16x8*)&GL[aoff];
    }
#pragma unroll 2
    for (int ks = 0; ks < 20; ++ks) {
        const int cur = ks & 1, nxt = cur ^ 1;
        if (ks < 19) {
            whb[nxt] = bH[(ks + 1) * 64];
            wlb[nxt] = bL[(ks + 1) * 64];
            int c0 = (ks + 1) * 2 + hf;
            int aoff = (c0 * 32 + (l31 ^ (c0 & 7))) * 8;
            gahb[nxt] = *(const s16x8*)&GH[aoff];
            galb[nxt] = *(const s16x8*)&GL[aoff];
        }
        U4V wh; wh.q = whb[cur];
        U4V wl; wl.q = wlb[cur];
        acc2A = MFMA32(gahb[cur], wh.v, acc2A);
        acc2B = MFMA32(galb[cur], wh.v, acc2B);
        acc2B = MFMA32(gahb[cur], wl.v, acc2B);
    }

    const int jcol = wid * 32 + l31;
    float bj = bvec[jcol];
    float v[16];
#pragma unroll
    for (int r = 0; r < 16; ++r) {
        int e = (r & 3) + ((r >> 2) << 3) + (hf << 2);
        v[r] = acc2A[r] + acc2B[r] + csh[e] * bj;
    }

    __syncthreads();   // B2: all waves done reading G before S overwrites union

#pragma unroll
    for (int r = 0; r < 16; ++r) {
        int e = (r & 3) + ((r >> 2) << 3) + (hf << 2);
        sm.S[e * SST + jcol] = v[r];
    }
    __syncthreads();   // B3

    // row sweeps: half-wave hw (0..15) handles rows 2hw, 2hw+1
    const int hw = tid >> 5;
    const int li = tid & 31;
    if (hw < 16) {
#pragma unroll
        for (int rr = 0; rr < 2; ++rr) {
            int row = 2 * hw + rr;
            float x[10];
            float m = -3.4e38f;
#pragma unroll
            for (int q = 0; q < 10; ++q) {
                x[q] = sm.S[row * SST + li + 32 * q];
                m = fmaxf(m, x[q]);
            }
#pragma unroll
            for (int off = 16; off; off >>= 1) m = fmaxf(m, __shfl_xor(m, off, 64));
            float ssum = 0.f;
#pragma unroll
            for (int q = 0; q < 10; ++q) ssum += __expf(x[q] - m);
#pragma unroll
            for (int off = 16; off; off >>= 1) ssum += __shfl_xor(ssum, off, 64);
            if (li == 0) { Mfin[row] = m; Ifin[row] = 1.0f / ssum; }
        }
    }
    __syncthreads();   // B4

    float wcol = 0.f;
#pragma unroll
    for (int r = 0; r < 16; ++r) {
        int e = (r & 3) + ((r >> 2) << 3) + (hf << 2);
        wcol += __expf(v[r] - Mfin[e]) * Ifin[e];
    }
    wcol += __shfl_xor(wcol, 32, 64);
    if (hf == 0) atomicAdd(&w[(size_t)i * N + jcol], wcol);
}

// ================= out[i][k] = sum_j w[i][j] * s[j][k], 2 i's per block ========
__global__ __launch_bounds__(320) void out_gemm_kernel(
    const float* __restrict__ w, const float* __restrict__ s,
    float* __restrict__ out)
{
    const int i0 = blockIdx.x * 2;
    const int k = threadIdx.x;
    const float* w0 = w + (size_t)i0 * N;
    const float* w1 = w0 + N;
    float a0 = 0.f, a1 = 0.f, b0 = 0.f, b1 = 0.f;
    for (int j = 0; j < N; j += 2) {
        float s0 = s[(size_t)j * N + k];
        float s1 = s[(size_t)(j + 1) * N + k];
        a0 += w0[j] * s0; a1 += w0[j + 1] * s1;
        b0 += w1[j] * s0; b1 += w1[j + 1] * s1;
    }
    out[(size_t)i0 * N + k] = a0 + a1;
    out[(size_t)(i0 + 1) * N + k] = b0 + b1;
}

extern "C" void kernel_launch(void* const* d_in, const int* in_sizes, int n_in,
                              void* d_out, int out_size, void* d_ws, size_t ws_size,
                              hipStream_t stream)
{
    const float* s    = (const float*)d_in[0];
    const float* fut  = (const float*)d_in[1];
    const float* W    = (const float*)d_in[2];
    const float* bvec = (const float*)d_in[3];
    float* out = (float*)d_out;

    char* base = (char*)d_ws;
    float* wbuf   = (float*)base;                        // NN floats (409600 B)
    float* colsum = (float*)(base + 409600);             // N floats  (1280 B)
    uint4* spH = (uint4*)(base + 410880);                // 204800 B
    uint4* spL = (uint4*)(base + 615680);                // 204800 B
    uint4* wpH = (uint4*)(base + 820480);                // 204800 B
    uint4* wpL = (uint4*)(base + 1025280);               // 204800 B

    prep_kernel<<<dim3(201), dim3(256), 0, stream>>>(
        s, W, wbuf, colsum, spH, spL, wpH, wpL);

    fused_kernel<<<dim3(3200), dim3(640), 0, stream>>>(
        fut, spH, spL, wpH, wpL, bvec, colsum, wbuf);

    out_gemm_kernel<<<dim3(N / 2), dim3(320), 0, stream>>>(wbuf, s, out);
}

// Round 6
// 401.200 us; speedup vs baseline: 4.4281x; 4.4281x over previous
//
#include <hip/hip_runtime.h>
#include <hip/hip_bf16.h>
#include <math.h>

#define N 320
#define NN (N * N)          // 102400
#define SST 324             // LDS fp32 row stride for S scratch

typedef float f32x16 __attribute__((ext_vector_type(16)));
typedef short s16x8  __attribute__((ext_vector_type(8)));

#define MFMA32(a, b, c) __builtin_amdgcn_mfma_f32_32x32x16_bf16((a), (b), (c), 0, 0, 0)

union U4V { uint4 q; s16x8 v; };
union UAV { unsigned u[4]; s16x8 v; };

// truncation split via v_perm_b32: x = hi + lo, both bf16 (combined rel err ~2^-16)
__device__ inline void split2p(float x0, float x1, unsigned& hi, unsigned& lo) {
    unsigned u0 = __float_as_uint(x0), u1 = __float_as_uint(x1);
    hi = __builtin_amdgcn_perm(u1, u0, 0x07060302u);
    float d0 = x0 - __uint_as_float(u0 & 0xFFFF0000u);
    float d1 = x1 - __uint_as_float(u1 & 0xFFFF0000u);
    lo = __builtin_amdgcn_perm(__float_as_uint(d1), __float_as_uint(d0), 0x07060302u);
}

// ================= merged prep kernel =================
__global__ __launch_bounds__(256) void prep_kernel(
    const float* __restrict__ s, const float* __restrict__ W,
    float* __restrict__ wbuf, float* __restrict__ colsum,
    uint4* __restrict__ spH, uint4* __restrict__ spL,
    uint4* __restrict__ wpH, uint4* __restrict__ wpL)
{
    const int blk = blockIdx.x;
    const int tid = threadIdx.x;

    if (blk < 100) {
        ((float4*)wbuf)[blk * 256 + tid] = make_float4(0.f, 0.f, 0.f, 0.f);
        return;
    }
    if (blk == 100) {
        for (int e = tid; e < N; e += 256) {
            float a0 = 0.f, a1 = 0.f, a2 = 0.f, a3 = 0.f;
            for (int t = 0; t < N; t += 4) {
                a0 += s[(size_t)(t + 0) * N + e];
                a1 += s[(size_t)(t + 1) * N + e];
                a2 += s[(size_t)(t + 2) * N + e];
                a3 += s[(size_t)(t + 3) * N + e];
            }
            colsum[e] = (a0 + a1) + (a2 + a3);
        }
        return;
    }
    if (blk <= 150) {
        int fb = (blk - 101) * 4 + (tid >> 6);   // frag-block 0..199 = et*20+ts
        int l = tid & 63;
        int et = fb / 20, ts = fb % 20;
        int e = et * 32 + (l & 31);
        int t0 = ts * 16 + (l >> 5) * 8;
        unsigned hi[4], lo[4];
#pragma unroll
        for (int d = 0; d < 4; ++d)
            split2p(s[(size_t)(t0 + 2 * d) * N + e], s[(size_t)(t0 + 2 * d + 1) * N + e],
                    hi[d], lo[d]);
        spH[fb * 64 + l] = make_uint4(hi[0], hi[1], hi[2], hi[3]);
        spL[fb * 64 + l] = make_uint4(lo[0], lo[1], lo[2], lo[3]);
        return;
    }
    {
        int fb = (blk - 151) * 4 + (tid >> 6);   // frag-block 0..199 = jt*20+ks
        int l = tid & 63;
        int jt = fb / 20, ks = fb % 20;
        int j = jt * 32 + (l & 31);
        int k0 = ks * 16 + (l >> 5) * 8;
        const float* wr = W + (size_t)j * N + k0;
        unsigned hi[4], lo[4];
#pragma unroll
        for (int d = 0; d < 4; ++d) split2p(wr[2 * d], wr[2 * d + 1], hi[d], lo[d]);
        wpH[fb * 64 + l] = make_uint4(hi[0], hi[1], hi[2], hi[3]);
        wpL[fb * 64 + l] = make_uint4(lo[0], lo[1], lo[2], lo[3]);
    }
}

// ---- phase-A pipeline macros (all arrays constant-indexed; no runtime idx) ----
#define LOAD_A(FB, AHV, ALV, TS) do {                                          \
    const float* fp_ = fbase + (size_t)((TS) * 16) * N;                        \
    _Pragma("unroll")                                                          \
    for (int j_ = 0; j_ < 8; ++j_) FB[j_] = fp_[(size_t)j_ * N];               \
    AHV = aH[(TS) * 64]; ALV = aL[(TS) * 64];                                  \
} while (0)

#define CONS_A(FB, AHV, ALV) do {                                              \
    UAV bh_, bl_;                                                              \
    _Pragma("unroll")                                                          \
    for (int d_ = 0; d_ < 4; ++d_)                                             \
        split2p(FB[2 * d_], FB[2 * d_ + 1], bh_.u[d_], bl_.u[d_]);             \
    U4V ah_; ah_.q = AHV; U4V al_; al_.q = ALV;                                \
    accA = MFMA32(ah_.v, bh_.v, accA);                                         \
    accB = MFMA32(al_.v, bh_.v, accB);                                         \
    accB = MFMA32(ah_.v, bl_.v, accB);                                         \
} while (0)

// ---- phase-B pipeline macros ----
#define LOAD_B(WHV, WLV, GAH, GAL, KS) do {                                    \
    WHV = bH[(KS) * 64]; WLV = bL[(KS) * 64];                                  \
    int c0_ = (KS) * 2 + hf;                                                   \
    int aoff_ = (c0_ * 32 + (l31 ^ (c0_ & 7))) * 8;                            \
    GAH = *(const s16x8*)&GH[aoff_];                                           \
    GAL = *(const s16x8*)&GL[aoff_];                                           \
} while (0)

#define CONS_B(WHV, WLV, GAH, GAL) do {                                        \
    U4V wh_; wh_.q = WHV; U4V wl_; wl_.q = WLV;                                \
    acc2A = MFMA32(GAH, wh_.v, acc2A);                                         \
    acc2B = MFMA32(GAL, wh_.v, acc2B);                                         \
    acc2B = MFMA32(GAH, wl_.v, acc2B);                                         \
} while (0)

// ================= fused MFMA kernel: per (e-slab 32, i) =================
// 1-D grid (3200), XCD swizzle: all 10 e-slabs of one i on one XCD (L2 reuse of F_i).
__global__ __launch_bounds__(640, 4) void fused_kernel(
    const float* __restrict__ fut,
    const uint4* __restrict__ spH, const uint4* __restrict__ spL,
    const uint4* __restrict__ wpH, const uint4* __restrict__ wpL,
    const float* __restrict__ bvec, const float* __restrict__ colsum,
    float* __restrict__ w)
{
    const int bid = blockIdx.x;
    const int i   = (bid / 80) * 8 + (bid & 7);
    const int et  = (bid >> 3) % 10;
    const int tid = threadIdx.x;
    const int wid = tid >> 6;         // wave 0..9 = 32-wide column tile
    const int lane = tid & 63;
    const int l31 = lane & 31;
    const int hf  = lane >> 5;

    __shared__ union {
        unsigned short G[2][40 * 32 * 8];   // [hi/lo] 20KB each, swizzled frag-linear
        float S[32 * SST];                  // softmax scratch
    } sm;
    __shared__ float csh[32];
    __shared__ float Mfin[32];
    __shared__ float Ifin[32];

    if (tid < 32) csh[tid] = colsum[et * 32 + tid];

    // ---------------- phase A: G = s^T @ F_i ----------------
    f32x16 accA, accB;
#pragma unroll
    for (int r = 0; r < 16; ++r) { accA[r] = 0.f; accB[r] = 0.f; }

    const float* fbase = fut + (size_t)i * NN + (size_t)(hf * 8) * N + wid * 32 + l31;
    const uint4* aH = spH + (size_t)(et * 20) * 64 + lane;
    const uint4* aL = spL + (size_t)(et * 20) * 64 + lane;

    float fA[8], fB[8];
    uint4 ahA, alA, ahB, alB;
    LOAD_A(fA, ahA, alA, 0);
    for (int ts = 0; ts < 20; ts += 2) {
        LOAD_A(fB, ahB, alB, ts + 1);
        CONS_A(fA, ahA, alA);
        if (ts + 2 < 20) LOAD_A(fA, ahA, alA, ts + 2);
        CONS_A(fB, ahB, alB);
    }

    // G -> LDS bf16 hi/lo in frag-linear swizzled layout (R4-verified: 0 conflicts)
    {
        const int c  = wid * 4 + (l31 >> 3);
        const int jj = l31 & 7;
        const int sw = c & 7;
        unsigned short* GH = sm.G[0];
        unsigned short* GL = sm.G[1];
#pragma unroll
        for (int r = 0; r < 16; ++r) {
            int e = (r & 3) + ((r >> 2) << 3) + (hf << 2);
            float x = accA[r] + accB[r];
            unsigned u = __float_as_uint(x);
            float d = x - __uint_as_float(u & 0xFFFF0000u);
            int off = (c * 32 + (e ^ sw)) * 8 + jj;
            GH[off] = (unsigned short)(u >> 16);
            GL[off] = (unsigned short)(__float_as_uint(d) >> 16);
        }
    }
    __syncthreads();   // B1: G + csh visible

    // ---------------- phase B: S = G @ W^T (+ bias) ----------------
    f32x16 acc2A, acc2B;
#pragma unroll
    for (int r = 0; r < 16; ++r) { acc2A[r] = 0.f; acc2B[r] = 0.f; }

    const uint4* bH = wpH + (size_t)(wid * 20) * 64 + lane;
    const uint4* bL = wpL + (size_t)(wid * 20) * 64 + lane;
    const unsigned short* GH = sm.G[0];
    const unsigned short* GL = sm.G[1];

    uint4 whA, wlA, whB, wlB;
    s16x8 gahA, galA, gahB, galB;
    LOAD_B(whA, wlA, gahA, galA, 0);
    for (int ks = 0; ks < 20; ks += 2) {
        LOAD_B(whB, wlB, gahB, galB, ks + 1);
        CONS_B(whA, wlA, gahA, galA);
        if (ks + 2 < 20) LOAD_B(whA, wlA, gahA, galA, ks + 2);
        CONS_B(whB, wlB, gahB, galB);
    }

    const int jcol = wid * 32 + l31;
    float bj = bvec[jcol];
    float v[16];
#pragma unroll
    for (int r = 0; r < 16; ++r) {
        int e = (r & 3) + ((r >> 2) << 3) + (hf << 2);
        v[r] = acc2A[r] + acc2B[r] + csh[e] * bj;
    }

    __syncthreads();   // B2: all waves done reading G before S overwrites union

#pragma unroll
    for (int r = 0; r < 16; ++r) {
        int e = (r & 3) + ((r >> 2) << 3) + (hf << 2);
        sm.S[e * SST + jcol] = v[r];
    }
    __syncthreads();   // B3

    // row sweeps: half-wave hw (0..15) handles rows 2hw, 2hw+1
    const int hw = tid >> 5;
    const int li = tid & 31;
    if (hw < 16) {
#pragma unroll
        for (int rr = 0; rr < 2; ++rr) {
            int row = 2 * hw + rr;
            float x[10];
            float m = -3.4e38f;
#pragma unroll
            for (int q = 0; q < 10; ++q) {
                x[q] = sm.S[row * SST + li + 32 * q];
                m = fmaxf(m, x[q]);
            }
#pragma unroll
            for (int off = 16; off; off >>= 1) m = fmaxf(m, __shfl_xor(m, off, 64));
            float ssum = 0.f;
#pragma unroll
            for (int q = 0; q < 10; ++q) ssum += __expf(x[q] - m);
#pragma unroll
            for (int off = 16; off; off >>= 1) ssum += __shfl_xor(ssum, off, 64);
            if (li == 0) { Mfin[row] = m; Ifin[row] = 1.0f / ssum; }
        }
    }
    __syncthreads();   // B4

    float wcol = 0.f;
#pragma unroll
    for (int r = 0; r < 16; ++r) {
        int e = (r & 3) + ((r >> 2) << 3) + (hf << 2);
        wcol += __expf(v[r] - Mfin[e]) * Ifin[e];
    }
    wcol += __shfl_xor(wcol, 32, 64);
    if (hf == 0) atomicAdd(&w[(size_t)i * N + jcol], wcol);
}

// ================= out[i][k] = sum_j w[i][j] * s[j][k], 2 i's per block ========
__global__ __launch_bounds__(320) void out_gemm_kernel(
    const float* __restrict__ w, const float* __restrict__ s,
    float* __restrict__ out)
{
    const int i0 = blockIdx.x * 2;
    const int k = threadIdx.x;
    const float* w0 = w + (size_t)i0 * N;
    const float* w1 = w0 + N;
    float a0 = 0.f, a1 = 0.f, b0 = 0.f, b1 = 0.f;
    for (int j = 0; j < N; j += 2) {
        float s0 = s[(size_t)j * N + k];
        float s1 = s[(size_t)(j + 1) * N + k];
        a0 += w0[j] * s0; a1 += w0[j + 1] * s1;
        b0 += w1[j] * s0; b1 += w1[j + 1] * s1;
    }
    out[(size_t)i0 * N + k] = a0 + a1;
    out[(size_t)(i0 + 1) * N + k] = b0 + b1;
}

extern "C" void kernel_launch(void* const* d_in, const int* in_sizes, int n_in,
                              void* d_out, int out_size, void* d_ws, size_t ws_size,
                              hipStream_t stream)
{
    const float* s    = (const float*)d_in[0];
    const float* fut  = (const float*)d_in[1];
    const float* W    = (const float*)d_in[2];
    const float* bvec = (const float*)d_in[3];
    float* out = (float*)d_out;

    char* base = (char*)d_ws;
    float* wbuf   = (float*)base;                        // NN floats (409600 B)
    float* colsum = (float*)(base + 409600);             // N floats  (1280 B)
    uint4* spH = (uint4*)(base + 410880);                // 204800 B
    uint4* spL = (uint4*)(base + 615680);                // 204800 B
    uint4* wpH = (uint4*)(base + 820480);                // 204800 B
    uint4* wpL = (uint4*)(base + 1025280);               // 204800 B

    prep_kernel<<<dim3(201), dim3(256), 0, stream>>>(
        s, W, wbuf, colsum, spH, spL, wpH, wpL);

    fused_kernel<<<dim3(3200), dim3(640), 0, stream>>>(
        fut, spH, spL, wpH, wpL, bvec, colsum, wbuf);

    out_gemm_kernel<<<dim3(N / 2), dim3(320), 0, stream>>>(wbuf, s, out);
}